// Round 3
// baseline (829.650 us; speedup 1.0000x reference)
//
#include <hip/hip_runtime.h>
#include <hip/hip_bf16.h>

#define NB   8
#define SS   2048
#define DD   1024
#define DFFN 4096
#define MTOT (NB*SS)   // 16384

typedef unsigned short u16;
typedef __attribute__((ext_vector_type(4))) float f32x4;
typedef __attribute__((ext_vector_type(8))) short bf16x8;
typedef __attribute__((ext_vector_type(4))) unsigned short u16x4;
typedef __attribute__((ext_vector_type(8))) unsigned short u16x8;

__device__ __forceinline__ u16 f2bf(float f) {
  union { float f; unsigned u; } c; c.f = f;
  unsigned r = c.u + 0x7FFFu + ((c.u >> 16) & 1u);
  return (u16)(r >> 16);
}

__device__ __forceinline__ void gload16(const void* g, void* l) {
  __builtin_amdgcn_global_load_lds(
      (const __attribute__((address_space(1))) void*)(unsigned long long)g,
      (__attribute__((address_space(3))) void*)(unsigned)(unsigned long long)l,
      16, 0, 0);
}

// ---------------------------------------------------------------------------
// 256x256 GEMM-BT, 8 waves (2x4), per-wave 128x64. BK=32, 4-deep LDS ring.
// K-step split in 2 phases: {reads for this phase's MFMA; stage half-tile;
// [vmcnt(8) in phase 1]; barrier; 16 MFMA; barrier}. vmcnt(8) keeps 4
// half-tiles (8 loads) in flight across barriers; tile t+1 is guaranteed
// landed one K-step early. Epilogue stages C-tile in LDS (swizzled) then
// writes 16B/lane contiguous (kills partial-line write amplification).
// ---------------------------------------------------------------------------
template<int EBIAS, int EGELU, int ESCALE, int EROWSCALE, int OUTMODE, int ETRANS, int CSKIP, int CK>
__global__ __launch_bounds__(512, 2)
void gemm256(const u16* __restrict__ A, const u16* __restrict__ B,
             const float* __restrict__ bias, const float* __restrict__ rowscale,
             void* __restrict__ C,
             int M, int N, int K, int lda, int ldb, int ldc, float scale,
             long long sA, long long sB, long long sC, int sRS)
{
  __shared__ __align__(1024) u16 smem[65536];   // 128 KB

  // bijective XCD swizzle over x*y (z = batch)
  const int nwg = gridDim.x * gridDim.y;
  const int orig = blockIdx.y * gridDim.x + blockIdx.x;
  const int q = nwg >> 3, r = nwg & 7;
  const int xcd = orig & 7, pos0 = orig >> 3;
  const int wg = (xcd < r ? xcd * (q + 1) : r * (q + 1) + (xcd - r) * q) + pos0;
  const int bx = wg % gridDim.x, by = wg / gridDim.x;
  const int row0 = by * 256, col0 = bx * 256;
  if (CSKIP && col0 > row0 + 255) return;

  const int z = blockIdx.z;
  A += (size_t)z * sA;
  B += (size_t)z * sB;

  int nkt = K >> 5;
  if (CK) { int lim = (row0 + 256) >> 5; if (lim < nkt) nkt = lim; }

  const int tid  = threadIdx.x;
  const int wid  = tid >> 6;
  const int lane = tid & 63;
  const int wr = wid >> 2, wc = wid & 3;

  // staging source (pre-swizzled): lane l -> row +(l>>2), unit (l&3)^((l>>3)&3)
  const int srow = wid * 16 + (lane >> 2);
  const int sunit = (lane & 3) ^ ((lane >> 3) & 3);
  const char* gA = (const char*)A + ((size_t)(row0 + srow) * lda + sunit * 8) * 2;
  const char* gB = (const char*)B + ((size_t)(col0 + srow) * ldb + sunit * 8) * 2;
  char* lbase = (char*)smem;
  const size_t ldab = (size_t)128 * lda * 2;
  const size_t ldbb = (size_t)128 * ldb * 2;

  #define SHA(t2) { char* lb = lbase + ((t2) & 3) * 32768; size_t kb = (size_t)(t2) * 64; \
      gload16(gA + kb,        lb + wid * 1024);                                          \
      gload16(gA + kb + ldab, lb + 8192 + wid * 1024); }
  #define SHB(t2) { char* lb = lbase + ((t2) & 3) * 32768; size_t kb = (size_t)(t2) * 64; \
      gload16(gB + kb,        lb + 16384 + wid * 1024);                                   \
      gload16(gB + kb + ldbb, lb + 16384 + 8192 + wid * 1024); }

  const int fr = lane & 15;
  const int rd_off = fr * 64 + ((lane >> 4) & 3) * 16;
  const int xm = ((lane >> 1) & 3) << 4;
  const int aoff = wr * 8192;
  const int boff = 16384 + wc * 4096;

  f32x4 acc[8][4] = {};
  bf16x8 aLo[4], aHi[4], bb[4];

  // prologue: halves A0,B0,A1,B1,A2,B2 (12 loads); vmcnt(8) -> tile 0 landed
  SHA(0); SHB(0); SHA(1); SHB(1); SHA(2); SHB(2);
  asm volatile("s_waitcnt vmcnt(8)" ::: "memory");
  asm volatile("s_barrier" ::: "memory");

  for (int t = 0; t < nkt; ++t) {
    const char* cbuf = (const char*)smem + (t & 3) * 32768;
    // ---- phase 0: reads A0-3(t), B0-3(t); stage A(t+3) ----
#pragma unroll
    for (int m = 0; m < 4; ++m)
      aLo[m] = *(const bf16x8*)(cbuf + ((aoff + m * 1024 + rd_off) ^ xm));
#pragma unroll
    for (int n = 0; n < 4; ++n)
      bb[n] = *(const bf16x8*)(cbuf + ((boff + n * 1024 + rd_off) ^ xm));
    if (t + 3 < nkt) SHA(t + 3);
    asm volatile("s_barrier" ::: "memory");
    __builtin_amdgcn_s_setprio(1);
#pragma unroll
    for (int m = 0; m < 4; ++m)
#pragma unroll
      for (int n = 0; n < 4; ++n)
        acc[m][n] = __builtin_amdgcn_mfma_f32_16x16x32_bf16(aLo[m], bb[n], acc[m][n], 0, 0, 0);
    __builtin_amdgcn_s_setprio(0);
    asm volatile("s_barrier" ::: "memory");
    // ---- phase 1: reads A4-7(t); stage B(t+3); counted vmcnt ----
#pragma unroll
    for (int m = 0; m < 4; ++m)
      aHi[m] = *(const bf16x8*)(cbuf + ((aoff + (m + 4) * 1024 + rd_off) ^ xm));
    if (t + 3 < nkt) SHB(t + 3);
    asm volatile("s_waitcnt vmcnt(8)" ::: "memory");
    asm volatile("s_barrier" ::: "memory");
    __builtin_amdgcn_s_setprio(1);
#pragma unroll
    for (int m = 0; m < 4; ++m)
#pragma unroll
      for (int n = 0; n < 4; ++n)
        acc[m + 4][n] = __builtin_amdgcn_mfma_f32_16x16x32_bf16(aHi[m], bb[n], acc[m + 4][n], 0, 0, 0);
    __builtin_amdgcn_s_setprio(0);
    asm volatile("s_barrier" ::: "memory");
  }
  #undef SHA
  #undef SHB

  // ---- epilogue via LDS (drain remaining stages first!) ----
  asm volatile("s_waitcnt vmcnt(0)" ::: "memory");
  __syncthreads();

  char* sm = (char*)smem;
  const int r4 = (lane >> 4) * 4;

  if (OUTMODE == 1) {
    // f32 out: two col-half passes (256 lines x 512 B each)
#pragma unroll
    for (int p = 0; p < 2; ++p) {
      if ((wc >> 1) == p) {
#pragma unroll
        for (int n = 0; n < 4; ++n) {
          const int col = col0 + wc * 64 + n * 16 + fr;
          const int pcol = (wc & 1) * 64 + n * 16 + fr;
          float bia = EBIAS ? bias[col] : 0.0f;
#pragma unroll
          for (int m = 0; m < 8; ++m) {
#pragma unroll
            for (int j = 0; j < 4; ++j) {
              const int line = wr * 128 + m * 16 + r4 + j;
              float xv = acc[m][n][j];
              if (EBIAS)     xv += bia;
              if (ESCALE)    xv *= scale;
              if (EROWSCALE) xv *= rowscale[z * sRS + row0 + line];
              if (EGELU)     xv = 0.5f * xv * (1.0f + erff(xv * 0.70710678118f));
              *(float*)(sm + ((line * 512 + pcol * 4) ^ ((line & 12) << 3))) = xv;
            }
          }
        }
      }
      __syncthreads();
      float* Cb = (float*)C + (size_t)z * sC;
#pragma unroll
      for (int i = 0; i < 16; ++i) {
        const int o = i * 8192 + tid * 16;
        const int line = o >> 9, ps = o & 511;
        f32x4 v = *(const f32x4*)(sm + ((line * 512 + ps) ^ ((line & 12) << 3)));
        *(f32x4*)((char*)(Cb + (size_t)(row0 + line) * ldc + col0 + p * 128) + ps) = v;
      }
      __syncthreads();
    }
  } else if (ETRANS) {
    // transposed bf16 out: LDS[line=col][pos=row*2]
#pragma unroll
    for (int n = 0; n < 4; ++n) {
      const int col = col0 + wc * 64 + n * 16 + fr;
      const int line = wc * 64 + n * 16 + fr;
      float bia = EBIAS ? bias[col] : 0.0f;
#pragma unroll
      for (int m = 0; m < 8; ++m) {
        const int rb = wr * 128 + m * 16 + r4;
        u16x4 pk;
#pragma unroll
        for (int j = 0; j < 4; ++j) {
          float xv = acc[m][n][j];
          if (EBIAS)     xv += bia;
          if (ESCALE)    xv *= scale;
          if (EROWSCALE) xv *= rowscale[z * sRS + row0 + rb + j];
          pk[j] = f2bf(xv);
        }
        *(u16x4*)(sm + ((line * 512 + rb * 2) ^ ((line & 15) << 4))) = pk;
      }
    }
    __syncthreads();
    u16* Cb = (u16*)C + (size_t)(row0 >> 11) * (DD * SS) + (row0 & (SS - 1));
#pragma unroll
    for (int i = 0; i < 16; ++i) {
      const int o = i * 8192 + tid * 16;
      const int line = o >> 9, ps = o & 511;
      f32x4 v = *(const f32x4*)(sm + ((line * 512 + ps) ^ ((line & 15) << 4)));
      *(f32x4*)((char*)(Cb + (size_t)(col0 + line) * SS) + ps) = v;
    }
  } else {
    // 2-byte outputs (bf16 OUTMODE=0, f16 OUTMODE=2): LDS[line=row][pos=col*2]
#pragma unroll
    for (int n = 0; n < 4; ++n) {
      const int col = col0 + wc * 64 + n * 16 + fr;
      const int pc = (wc * 64 + n * 16 + fr) * 2;
      float bia = EBIAS ? bias[col] : 0.0f;
#pragma unroll
      for (int m = 0; m < 8; ++m) {
#pragma unroll
        for (int j = 0; j < 4; ++j) {
          const int line = wr * 128 + m * 16 + r4 + j;
          float xv = acc[m][n][j];
          if (EBIAS)     xv += bia;
          if (ESCALE)    xv *= scale;
          if (EROWSCALE) xv *= rowscale[z * sRS + row0 + line];
          if (EGELU)     xv = 0.5f * xv * (1.0f + erff(xv * 0.70710678118f));
          u16 u;
          if (OUTMODE == 2) { union { u16 s; _Float16 h; } cu; cu.h = (_Float16)xv; u = cu.s; }
          else u = f2bf(xv);
          *(u16*)(sm + ((line * 512 + pc) ^ ((line & 12) << 3))) = u;
        }
      }
    }
    __syncthreads();
    u16* Cb = (u16*)C + (size_t)z * sC + col0;
#pragma unroll
    for (int i = 0; i < 16; ++i) {
      const int o = i * 8192 + tid * 16;
      const int line = o >> 9, ps = o & 511;
      f32x4 v = *(const f32x4*)(sm + ((line * 512 + ps) ^ ((line & 12) << 3)));
      *(f32x4*)((char*)(Cb + (size_t)(row0 + line) * ldc) + ps) = v;
    }
  }
}

// f32 -> bf16 convert, 4 elems/thread
__global__ __launch_bounds__(256) void cvt_bf16_k(const float* __restrict__ in, u16* __restrict__ out, int n4) {
  int i = blockIdx.x * blockDim.x + threadIdx.x;
  if (i < n4) {
    float4 v = ((const float4*)in)[i];
    u16x4 o;
    o.x = f2bf(v.x); o.y = f2bf(v.y); o.z = f2bf(v.z); o.w = f2bf(v.w);
    ((u16x4*)out)[i] = o;
  }
}

// batched row softmax over f16 scores, in-place rewrite as unnormalized bf16 P
__global__ __launch_bounds__(256) void softmax_k(u16* __restrict__ sc, float* __restrict__ rinv, int rows0) {
  const int widx = blockIdx.x * 4 + (threadIdx.x >> 6);
  const int lane = threadIdx.x & 63;
  u16* row = sc + (size_t)widx * SS;
  const int L = (widx & (SS - 1)) + 1;
  float mx = -1e30f;
  for (int k = 0; k < 4; ++k) {
    const int j0 = k * 512 + lane * 8;
    if (j0 < L) {
      u16x8 v = *(const u16x8*)(row + j0);
      int lim = L - j0; if (lim > 8) lim = 8;
#pragma unroll
      for (int e = 0; e < 8; ++e) {
        if (e < lim) { union { u16 u; _Float16 h; } c; c.u = v[e]; mx = fmaxf(mx, (float)c.h); }
      }
    }
  }
#pragma unroll
  for (int o = 32; o >= 1; o >>= 1) mx = fmaxf(mx, __shfl_xor(mx, o));
  float s = 0.0f;
  for (int k = 0; k < 4; ++k) {
    const int j0 = k * 512 + lane * 8;
    u16x8 v = *(const u16x8*)(row + j0);
    u16x8 w;
#pragma unroll
    for (int e = 0; e < 8; ++e) {
      const int j = j0 + e;
      float ev = 0.0f;
      if (j < L) { union { u16 u; _Float16 h; } c; c.u = v[e]; ev = __expf((float)c.h - mx); s += ev; }
      w[e] = f2bf(ev);
    }
    *(u16x8*)(row + j0) = w;
  }
#pragma unroll
  for (int o = 32; o >= 1; o >>= 1) s += __shfl_xor(s, o);
  if (lane == 0) rinv[rows0 + widx] = 1.0f / s;
}

extern "C" void kernel_launch(void* const* d_in, const int* in_sizes, int n_in,
                              void* d_out, int out_size, void* d_ws, size_t ws_size,
                              hipStream_t stream) {
  const float* x  = (const float*)d_in[0];
  const float* Wq = (const float*)d_in[1];
  const float* bq = (const float*)d_in[2];
  const float* Wk = (const float*)d_in[3];
  const float* bk = (const float*)d_in[4];
  const float* Wv = (const float*)d_in[5];
  const float* bv = (const float*)d_in[6];
  const float* W1 = (const float*)d_in[7];
  const float* b1 = (const float*)d_in[8];
  const float* W2 = (const float*)d_in[9];
  const float* b2 = (const float*)d_in[10];

  char* ws = (char*)d_ws;
  u16*  xb   = (u16*)(ws);                       // 32 MB (later: att)
  u16*  Wqb  = (u16*)(ws + 33554432);
  u16*  Wkb  = (u16*)(ws + 35651584);
  u16*  Wvb  = (u16*)(ws + 37748736);
  u16*  W1b  = (u16*)(ws + 39845888);
  u16*  W2b  = (u16*)(ws + 48234496);
  u16*  Qb   = (u16*)(ws + 56623104);            // 32 MB
  u16*  Kb   = (u16*)(ws + 90177536);            // 32 MB
  u16*  Vtb  = (u16*)(ws + 123731968);           // 32 MB
  float* rinv = (float*)(ws + 157286400);        // 64 KB
  u16*  big  = (u16*)(ws + 157351936);           // scores/P region; later h
  u16*  att  = xb;

  const size_t base = 157351936ull;
  const size_t avail = ws_size > base ? ws_size - base : 0;
  int GB = 8; while (GB > 1 && (size_t)GB * 8388608ull > avail) GB >>= 1;
  int MC = 8192; while (MC > 2048 && (size_t)MC * 8192ull > avail) MC >>= 1;

  // --- converts ---
  cvt_bf16_k<<<MTOT * DD / 4 / 256, 256, 0, stream>>>(x, xb, MTOT * DD / 4);
  cvt_bf16_k<<<DD * DD / 4 / 256, 256, 0, stream>>>(Wq, Wqb, DD * DD / 4);
  cvt_bf16_k<<<DD * DD / 4 / 256, 256, 0, stream>>>(Wk, Wkb, DD * DD / 4);
  cvt_bf16_k<<<DD * DD / 4 / 256, 256, 0, stream>>>(Wv, Wvb, DD * DD / 4);
  cvt_bf16_k<<<DFFN * DD / 4 / 256, 256, 0, stream>>>(W1, W1b, DFFN * DD / 4);
  cvt_bf16_k<<<DFFN * DD / 4 / 256, 256, 0, stream>>>(W2, W2b, DFFN * DD / 4);

  // --- QKV projections ---
  gemm256<1,0,0,0,0,0,0,0><<<dim3(DD/256, MTOT/256), 512, 0, stream>>>(
      xb, Wqb, bq, nullptr, (void*)Qb, MTOT, DD, DD, DD, DD, DD, 0.f, 0, 0, 0, 0);
  gemm256<1,0,0,0,0,0,0,0><<<dim3(DD/256, MTOT/256), 512, 0, stream>>>(
      xb, Wkb, bk, nullptr, (void*)Kb, MTOT, DD, DD, DD, DD, DD, 0.f, 0, 0, 0, 0);
  gemm256<1,0,0,0,0,1,0,0><<<dim3(DD/256, MTOT/256), 512, 0, stream>>>(
      xb, Wvb, bv, nullptr, (void*)Vtb, MTOT, DD, DD, DD, DD, DD, 0.f, 0, 0, 0, 0);

  // --- attention, batched over z in groups of GB ---
  for (int b0 = 0; b0 < NB; b0 += GB) {
    gemm256<0,0,1,0,2,0,1,0><<<dim3(SS/256, SS/256, GB), 512, 0, stream>>>(
        Qb + (size_t)b0 * SS * DD, Kb + (size_t)b0 * SS * DD, nullptr, nullptr,
        (void*)big, SS, SS, DD, DD, DD, SS, 0.03125f,
        (long long)SS * DD, (long long)SS * DD, (long long)SS * SS, 0);
    softmax_k<<<GB * SS / 4, 256, 0, stream>>>(big, rinv, b0 * SS);
    gemm256<0,0,0,1,0,0,0,1><<<dim3(DD/256, SS/256, GB), 512, 0, stream>>>(
        big, Vtb + (size_t)b0 * DD * SS, nullptr, rinv + (size_t)b0 * SS,
        (void*)(att + (size_t)b0 * SS * DD), SS, DD, SS, SS, SS, DD, 0.f,
        (long long)SS * SS, (long long)DD * SS, (long long)SS * DD, SS);
  }

  // --- MLP in chunks of MC rows ---
  for (int c = 0; c < MTOT / MC; ++c) {
    u16* h = big;
    gemm256<1,1,0,0,0,0,0,0><<<dim3(DFFN/256, MC/256), 512, 0, stream>>>(
        att + (size_t)c * MC * DD, W1b, b1, nullptr, (void*)h,
        MC, DFFN, DD, DD, DD, DFFN, 0.f, 0, 0, 0, 0);
    gemm256<1,0,0,0,1,0,0,0><<<dim3(DD/256, MC/256), 512, 0, stream>>>(
        h, W2b, b2, nullptr, (void*)((float*)d_out + (size_t)c * MC * DD),
        MC, DD, DFFN, DFFN, DFFN, DD, 0.f, 0, 0, 0, 0);
  }
}

// Round 4
// 825.977 us; speedup vs baseline: 1.0044x; 1.0044x over previous
//
#include <hip/hip_runtime.h>
#include <hip/hip_bf16.h>

#define NB   8
#define SS   2048
#define DD   1024
#define DFFN 4096
#define MTOT (NB*SS)   // 16384

typedef unsigned short u16;
typedef __attribute__((ext_vector_type(4))) float f32x4;
typedef __attribute__((ext_vector_type(8))) short bf16x8;
typedef __attribute__((ext_vector_type(4))) int i32x4;
typedef __attribute__((ext_vector_type(4))) unsigned short u16x4;
typedef __attribute__((ext_vector_type(8))) unsigned short u16x8;

__device__ __forceinline__ u16 f2bf(float f) {
  union { float f; unsigned u; } c; c.f = f;
  unsigned r = c.u + 0x7FFFu + ((c.u >> 16) & 1u);
  return (u16)(r >> 16);
}

__device__ __forceinline__ void gload16(const void* g, void* l) {
  __builtin_amdgcn_global_load_lds(
      (const __attribute__((address_space(1))) void*)(unsigned long long)g,
      (__attribute__((address_space(3))) void*)(unsigned)(unsigned long long)l,
      16, 0, 0);
}

// opaque LDS read: compiler can't see it as a DS op, so SIInsertWaitcnts
// cannot insert a protective vmcnt(0) (LDS-DMA hazard vs global_load_lds).
// We do our own counted vmcnt + lgkmcnt.
__device__ __forceinline__ bf16x8 dsr128(unsigned addr) {
  i32x4 r;
  asm volatile("ds_read_b128 %0, %1" : "=v"(r) : "v"(addr));
  return __builtin_bit_cast(bf16x8, r);
}

// ---------------------------------------------------------------------------
// 256x256 GEMM-BT, 8 waves (2x4), per-wave 128x64. BK=32, 4-deep LDS ring.
// 2 phases/K-step, 16 MFMA per barrier-pair, counted vmcnt(8) (never drains
// in the main loop), asm ds_read + lgkmcnt(0) + sched_barrier per rule #18.
// ---------------------------------------------------------------------------
template<int EBIAS, int EGELU, int ESCALE, int EROWSCALE, int OUTMODE, int ETRANS, int CSKIP, int CK>
__global__ __launch_bounds__(512, 2)
void gemm256(const u16* __restrict__ A, const u16* __restrict__ B,
             const float* __restrict__ bias, const float* __restrict__ rowscale,
             void* __restrict__ C,
             int M, int N, int K, int lda, int ldb, int ldc, float scale,
             long long sA, long long sB, long long sC, int sRS)
{
  __shared__ __align__(1024) u16 smem[65536];   // 128 KB

  // bijective XCD swizzle over x*y (z = batch)
  const int nwg = gridDim.x * gridDim.y;
  const int orig = blockIdx.y * gridDim.x + blockIdx.x;
  const int q = nwg >> 3, r = nwg & 7;
  const int xcd = orig & 7, pos0 = orig >> 3;
  const int wg = (xcd < r ? xcd * (q + 1) : r * (q + 1) + (xcd - r) * q) + pos0;
  const int bx = wg % gridDim.x, by = wg / gridDim.x;
  const int row0 = by * 256, col0 = bx * 256;
  if (CSKIP && col0 > row0 + 255) return;

  const int z = blockIdx.z;
  A += (size_t)z * sA;
  B += (size_t)z * sB;

  int nkt = K >> 5;
  if (CK) { int lim = (row0 + 256) >> 5; if (lim < nkt) nkt = lim; }
  // all instantiations here have nkt >= 8

  const int tid  = threadIdx.x;
  const int wid  = tid >> 6;
  const int lane = tid & 63;
  const int wr = wid >> 2, wc = wid & 3;

  // staging source (pre-swizzled): lane l -> row +(l>>2), unit (l&3)^((l>>3)&3)
  const int srow = wid * 16 + (lane >> 2);
  const int sunit = (lane & 3) ^ ((lane >> 3) & 3);
  const char* gA = (const char*)A + ((size_t)(row0 + srow) * lda + sunit * 8) * 2;
  const char* gB = (const char*)B + ((size_t)(col0 + srow) * ldb + sunit * 8) * 2;
  char* lbase = (char*)smem;
  const size_t ldab = (size_t)128 * lda * 2;
  const size_t ldbb = (size_t)128 * ldb * 2;

  #define SHA(t2) { char* lb = lbase + ((t2) & 3) * 32768; size_t kb = (size_t)(t2) * 64; \
      gload16(gA + kb,        lb + wid * 1024);                                          \
      gload16(gA + kb + ldab, lb + 8192 + wid * 1024); }
  #define SHB(t2) { char* lb = lbase + ((t2) & 3) * 32768; size_t kb = (size_t)(t2) * 64; \
      gload16(gB + kb,        lb + 16384 + wid * 1024);                                   \
      gload16(gB + kb + ldbb, lb + 16384 + 8192 + wid * 1024); }

  const int fr = lane & 15;
  const int rd_off = fr * 64 + ((lane >> 4) & 3) * 16;
  const int xm = ((lane >> 1) & 3) << 4;
  const int aoff = wr * 8192;
  const int boff = 16384 + wc * 4096;
  const unsigned sbase = (unsigned)(unsigned long long)(void*)smem;

  f32x4 acc[8][4] = {};
  bf16x8 aLo[4], aHi[4], bb[4];

  // prologue: stage tiles 0,1,2 (12 loads/wave); vmcnt(8) -> tile 0 landed
  SHA(0); SHB(0); SHA(1); SHB(1); SHA(2); SHB(2);
  asm volatile("s_waitcnt vmcnt(8)");
  asm volatile("s_barrier" ::: "memory");

  #define PHASE0_READS(cb)                                                    \
    _Pragma("unroll") for (int m = 0; m < 4; ++m)                             \
      aLo[m] = dsr128((cb) + ((aoff + m * 1024 + rd_off) ^ xm));              \
    _Pragma("unroll") for (int n = 0; n < 4; ++n)                             \
      bb[n] = dsr128((cb) + ((boff + n * 1024 + rd_off) ^ xm));
  #define PHASE1_READS(cb)                                                    \
    _Pragma("unroll") for (int m = 0; m < 4; ++m)                             \
      aHi[m] = dsr128((cb) + ((aoff + (m + 4) * 1024 + rd_off) ^ xm));
  #define MFMA_LO                                                             \
    _Pragma("unroll") for (int m = 0; m < 4; ++m)                             \
      _Pragma("unroll") for (int n = 0; n < 4; ++n)                           \
        acc[m][n] = __builtin_amdgcn_mfma_f32_16x16x32_bf16(aLo[m], bb[n], acc[m][n], 0, 0, 0);
  #define MFMA_HI                                                             \
    _Pragma("unroll") for (int m = 0; m < 4; ++m)                             \
      _Pragma("unroll") for (int n = 0; n < 4; ++n)                           \
        acc[m + 4][n] = __builtin_amdgcn_mfma_f32_16x16x32_bf16(aHi[m], bb[n], acc[m + 4][n], 0, 0, 0);
  #define LGK0_FENCE                                                          \
    asm volatile("s_waitcnt lgkmcnt(0)");                                     \
    __builtin_amdgcn_sched_barrier(0);

  // main loop: stages always issued (t+3 < nkt), vmcnt(8) never fully drains
  for (int t = 0; t < nkt - 3; ++t) {
    const unsigned cb = sbase + (t & 3) * 32768;
    // phase 0
    PHASE0_READS(cb);
    SHA(t + 3);
    asm volatile("s_barrier" ::: "memory");
    LGK0_FENCE;
    __builtin_amdgcn_s_setprio(1);
    MFMA_LO;
    __builtin_amdgcn_s_setprio(0);
    asm volatile("s_barrier" ::: "memory");
    // phase 1
    PHASE1_READS(cb);
    SHB(t + 3);
    asm volatile("s_waitcnt vmcnt(8)");   // tile t+1's 4 loads retired
    asm volatile("s_barrier" ::: "memory");
    LGK0_FENCE;
    __builtin_amdgcn_s_setprio(1);
    MFMA_HI;
    __builtin_amdgcn_s_setprio(0);
    asm volatile("s_barrier" ::: "memory");
  }

  // drain remaining stages (tiles nkt-2, nkt-1), then 3 tail steps, no staging
  asm volatile("s_waitcnt vmcnt(0)");
  asm volatile("s_barrier" ::: "memory");
  for (int t = nkt - 3; t < nkt; ++t) {
    const unsigned cb = sbase + (t & 3) * 32768;
    PHASE0_READS(cb);
    asm volatile("s_barrier" ::: "memory");
    LGK0_FENCE;
    __builtin_amdgcn_s_setprio(1);
    MFMA_LO;
    __builtin_amdgcn_s_setprio(0);
    asm volatile("s_barrier" ::: "memory");
    PHASE1_READS(cb);
    asm volatile("s_barrier" ::: "memory");
    LGK0_FENCE;
    __builtin_amdgcn_s_setprio(1);
    MFMA_HI;
    __builtin_amdgcn_s_setprio(0);
    asm volatile("s_barrier" ::: "memory");
  }
  #undef SHA
  #undef SHB
  #undef PHASE0_READS
  #undef PHASE1_READS
  #undef MFMA_LO
  #undef MFMA_HI
  #undef LGK0_FENCE

  // ---- epilogue via LDS (all stages retired above) ----
  __syncthreads();

  char* sm = (char*)smem;
  const int r4 = (lane >> 4) * 4;

  if (OUTMODE == 1) {
    // f32 out: two col-half passes (256 lines x 512 B each)
#pragma unroll
    for (int p = 0; p < 2; ++p) {
      if ((wc >> 1) == p) {
#pragma unroll
        for (int n = 0; n < 4; ++n) {
          const int col = col0 + wc * 64 + n * 16 + fr;
          const int pcol = (wc & 1) * 64 + n * 16 + fr;
          float bia = EBIAS ? bias[col] : 0.0f;
#pragma unroll
          for (int m = 0; m < 8; ++m) {
#pragma unroll
            for (int j = 0; j < 4; ++j) {
              const int line = wr * 128 + m * 16 + r4 + j;
              float xv = acc[m][n][j];
              if (EBIAS)     xv += bia;
              if (ESCALE)    xv *= scale;
              if (EROWSCALE) xv *= rowscale[z * sRS + row0 + line];
              if (EGELU)     xv = 0.5f * xv * (1.0f + erff(xv * 0.70710678118f));
              *(float*)(sm + ((line * 512 + pcol * 4) ^ ((line & 12) << 3))) = xv;
            }
          }
        }
      }
      __syncthreads();
      float* Cb = (float*)C + (size_t)z * sC;
#pragma unroll
      for (int i = 0; i < 16; ++i) {
        const int o = i * 8192 + tid * 16;
        const int line = o >> 9, ps = o & 511;
        f32x4 v = *(const f32x4*)(sm + ((line * 512 + ps) ^ ((line & 12) << 3)));
        *(f32x4*)((char*)(Cb + (size_t)(row0 + line) * ldc + col0 + p * 128) + ps) = v;
      }
      __syncthreads();
    }
  } else if (ETRANS) {
    // transposed bf16 out: LDS[line=col][pos=row*2]
#pragma unroll
    for (int n = 0; n < 4; ++n) {
      const int col = col0 + wc * 64 + n * 16 + fr;
      const int line = wc * 64 + n * 16 + fr;
      float bia = EBIAS ? bias[col] : 0.0f;
#pragma unroll
      for (int m = 0; m < 8; ++m) {
        const int rb = wr * 128 + m * 16 + r4;
        u16x4 pk;
#pragma unroll
        for (int j = 0; j < 4; ++j) {
          float xv = acc[m][n][j];
          if (EBIAS)     xv += bia;
          if (ESCALE)    xv *= scale;
          if (EROWSCALE) xv *= rowscale[z * sRS + row0 + rb + j];
          pk[j] = f2bf(xv);
        }
        *(u16x4*)(sm + ((line * 512 + rb * 2) ^ ((line & 15) << 4))) = pk;
      }
    }
    __syncthreads();
    u16* Cb = (u16*)C + (size_t)(row0 >> 11) * (DD * SS) + (row0 & (SS - 1));
#pragma unroll
    for (int i = 0; i < 16; ++i) {
      const int o = i * 8192 + tid * 16;
      const int line = o >> 9, ps = o & 511;
      f32x4 v = *(const f32x4*)(sm + ((line * 512 + ps) ^ ((line & 15) << 4)));
      *(f32x4*)((char*)(Cb + (size_t)(col0 + line) * SS) + ps) = v;
    }
  } else {
    // 2-byte outputs (bf16 OUTMODE=0, f16 OUTMODE=2): LDS[line=row][pos=col*2]
#pragma unroll
    for (int n = 0; n < 4; ++n) {
      const int col = col0 + wc * 64 + n * 16 + fr;
      const int pc = (wc * 64 + n * 16 + fr) * 2;
      float bia = EBIAS ? bias[col] : 0.0f;
#pragma unroll
      for (int m = 0; m < 8; ++m) {
#pragma unroll
        for (int j = 0; j < 4; ++j) {
          const int line = wr * 128 + m * 16 + r4 + j;
          float xv = acc[m][n][j];
          if (EBIAS)     xv += bia;
          if (ESCALE)    xv *= scale;
          if (EROWSCALE) xv *= rowscale[z * sRS + row0 + line];
          if (EGELU)     xv = 0.5f * xv * (1.0f + erff(xv * 0.70710678118f));
          u16 u;
          if (OUTMODE == 2) { union { u16 s; _Float16 h; } cu; cu.h = (_Float16)xv; u = cu.s; }
          else u = f2bf(xv);
          *(u16*)(sm + ((line * 512 + pc) ^ ((line & 12) << 3))) = u;
        }
      }
    }
    __syncthreads();
    u16* Cb = (u16*)C + (size_t)z * sC + col0;
#pragma unroll
    for (int i = 0; i < 16; ++i) {
      const int o = i * 8192 + tid * 16;
      const int line = o >> 9, ps = o & 511;
      f32x4 v = *(const f32x4*)(sm + ((line * 512 + ps) ^ ((line & 12) << 3)));
      *(f32x4*)((char*)(Cb + (size_t)(row0 + line) * ldc) + ps) = v;
    }
  }
}

// f32 -> bf16 convert, 4 elems/thread
__global__ __launch_bounds__(256) void cvt_bf16_k(const float* __restrict__ in, u16* __restrict__ out, int n4) {
  int i = blockIdx.x * blockDim.x + threadIdx.x;
  if (i < n4) {
    float4 v = ((const float4*)in)[i];
    u16x4 o;
    o.x = f2bf(v.x); o.y = f2bf(v.y); o.z = f2bf(v.z); o.w = f2bf(v.w);
    ((u16x4*)out)[i] = o;
  }
}

// batched row softmax over f16 scores, in-place rewrite as unnormalized bf16 P
__global__ __launch_bounds__(256) void softmax_k(u16* __restrict__ sc, float* __restrict__ rinv, int rows0) {
  const int widx = blockIdx.x * 4 + (threadIdx.x >> 6);
  const int lane = threadIdx.x & 63;
  u16* row = sc + (size_t)widx * SS;
  const int L = (widx & (SS - 1)) + 1;
  float mx = -1e30f;
  for (int k = 0; k < 4; ++k) {
    const int j0 = k * 512 + lane * 8;
    if (j0 < L) {
      u16x8 v = *(const u16x8*)(row + j0);
      int lim = L - j0; if (lim > 8) lim = 8;
#pragma unroll
      for (int e = 0; e < 8; ++e) {
        if (e < lim) { union { u16 u; _Float16 h; } c; c.u = v[e]; mx = fmaxf(mx, (float)c.h); }
      }
    }
  }
#pragma unroll
  for (int o = 32; o >= 1; o >>= 1) mx = fmaxf(mx, __shfl_xor(mx, o));
  float s = 0.0f;
  for (int k = 0; k < 4; ++k) {
    const int j0 = k * 512 + lane * 8;
    u16x8 v = *(const u16x8*)(row + j0);
    u16x8 w;
#pragma unroll
    for (int e = 0; e < 8; ++e) {
      const int j = j0 + e;
      float ev = 0.0f;
      if (j < L) { union { u16 u; _Float16 h; } c; c.u = v[e]; ev = __expf((float)c.h - mx); s += ev; }
      w[e] = f2bf(ev);
    }
    *(u16x8*)(row + j0) = w;
  }
#pragma unroll
  for (int o = 32; o >= 1; o >>= 1) s += __shfl_xor(s, o);
  if (lane == 0) rinv[rows0 + widx] = 1.0f / s;
}

extern "C" void kernel_launch(void* const* d_in, const int* in_sizes, int n_in,
                              void* d_out, int out_size, void* d_ws, size_t ws_size,
                              hipStream_t stream) {
  const float* x  = (const float*)d_in[0];
  const float* Wq = (const float*)d_in[1];
  const float* bq = (const float*)d_in[2];
  const float* Wk = (const float*)d_in[3];
  const float* bk = (const float*)d_in[4];
  const float* Wv = (const float*)d_in[5];
  const float* bv = (const float*)d_in[6];
  const float* W1 = (const float*)d_in[7];
  const float* b1 = (const float*)d_in[8];
  const float* W2 = (const float*)d_in[9];
  const float* b2 = (const float*)d_in[10];

  char* ws = (char*)d_ws;
  u16*  xb   = (u16*)(ws);                       // 32 MB (later: att)
  u16*  Wqb  = (u16*)(ws + 33554432);
  u16*  Wkb  = (u16*)(ws + 35651584);
  u16*  Wvb  = (u16*)(ws + 37748736);
  u16*  W1b  = (u16*)(ws + 39845888);
  u16*  W2b  = (u16*)(ws + 48234496);
  u16*  Qb   = (u16*)(ws + 56623104);            // 32 MB
  u16*  Kb   = (u16*)(ws + 90177536);            // 32 MB
  u16*  Vtb  = (u16*)(ws + 123731968);           // 32 MB
  float* rinv = (float*)(ws + 157286400);        // 64 KB
  u16*  big  = (u16*)(ws + 157351936);           // scores/P region; later h
  u16*  att  = xb;

  const size_t base = 157351936ull;
  const size_t avail = ws_size > base ? ws_size - base : 0;
  int GB = 8; while (GB > 1 && (size_t)GB * 8388608ull > avail) GB >>= 1;
  int MC = 8192; while (MC > 2048 && (size_t)MC * 8192ull > avail) MC >>= 1;

  // --- converts ---
  cvt_bf16_k<<<MTOT * DD / 4 / 256, 256, 0, stream>>>(x, xb, MTOT * DD / 4);
  cvt_bf16_k<<<DD * DD / 4 / 256, 256, 0, stream>>>(Wq, Wqb, DD * DD / 4);
  cvt_bf16_k<<<DD * DD / 4 / 256, 256, 0, stream>>>(Wk, Wkb, DD * DD / 4);
  cvt_bf16_k<<<DD * DD / 4 / 256, 256, 0, stream>>>(Wv, Wvb, DD * DD / 4);
  cvt_bf16_k<<<DFFN * DD / 4 / 256, 256, 0, stream>>>(W1, W1b, DFFN * DD / 4);
  cvt_bf16_k<<<DFFN * DD / 4 / 256, 256, 0, stream>>>(W2, W2b, DFFN * DD / 4);

  // --- QKV projections ---
  gemm256<1,0,0,0,0,0,0,0><<<dim3(DD/256, MTOT/256), 512, 0, stream>>>(
      xb, Wqb, bq, nullptr, (void*)Qb, MTOT, DD, DD, DD, DD, DD, 0.f, 0, 0, 0, 0);
  gemm256<1,0,0,0,0,0,0,0><<<dim3(DD/256, MTOT/256), 512, 0, stream>>>(
      xb, Wkb, bk, nullptr, (void*)Kb, MTOT, DD, DD, DD, DD, DD, 0.f, 0, 0, 0, 0);
  gemm256<1,0,0,0,0,1,0,0><<<dim3(DD/256, MTOT/256), 512, 0, stream>>>(
      xb, Wvb, bv, nullptr, (void*)Vtb, MTOT, DD, DD, DD, DD, DD, 0.f, 0, 0, 0, 0);

  // --- attention, batched over z in groups of GB ---
  for (int b0 = 0; b0 < NB; b0 += GB) {
    gemm256<0,0,1,0,2,0,1,0><<<dim3(SS/256, SS/256, GB), 512, 0, stream>>>(
        Qb + (size_t)b0 * SS * DD, Kb + (size_t)b0 * SS * DD, nullptr, nullptr,
        (void*)big, SS, SS, DD, DD, DD, SS, 0.03125f,
        (long long)SS * DD, (long long)SS * DD, (long long)SS * SS, 0);
    softmax_k<<<GB * SS / 4, 256, 0, stream>>>(big, rinv, b0 * SS);
    gemm256<0,0,0,1,0,0,0,1><<<dim3(DD/256, SS/256, GB), 512, 0, stream>>>(
        big, Vtb + (size_t)b0 * DD * SS, nullptr, rinv + (size_t)b0 * SS,
        (void*)(att + (size_t)b0 * SS * DD), SS, DD, SS, SS, SS, DD, 0.f,
        (long long)SS * SS, (long long)DD * SS, (long long)SS * DD, SS);
  }

  // --- MLP in chunks of MC rows ---
  for (int c = 0; c < MTOT / MC; ++c) {
    u16* h = big;
    gemm256<1,1,0,0,0,0,0,0><<<dim3(DFFN/256, MC/256), 512, 0, stream>>>(
        att + (size_t)c * MC * DD, W1b, b1, nullptr, (void*)h,
        MC, DFFN, DD, DD, DD, DFFN, 0.f, 0, 0, 0, 0);
    gemm256<1,0,0,0,1,0,0,0><<<dim3(DD/256, MC/256), 512, 0, stream>>>(
        h, W2b, b2, nullptr, (void*)((float*)d_out + (size_t)c * MC * DD),
        MC, DD, DFFN, DFFN, DFFN, DD, 0.f, 0, 0, 0, 0);
  }
}

// Round 5
// 715.439 us; speedup vs baseline: 1.1596x; 1.1545x over previous
//
#include <hip/hip_runtime.h>
#include <hip/hip_bf16.h>

#define NB   8
#define SS   2048
#define DD   1024
#define DFFN 4096
#define MTOT (NB*SS)   // 16384

typedef unsigned short u16;
typedef __attribute__((ext_vector_type(4))) float f32x4;
typedef __attribute__((ext_vector_type(8))) short bf16x8;
typedef __attribute__((ext_vector_type(4))) int i32x4;
typedef __attribute__((ext_vector_type(4))) unsigned short u16x4;
typedef __attribute__((ext_vector_type(8))) unsigned short u16x8;

__device__ __forceinline__ u16 f2bf(float f) {
  union { float f; unsigned u; } c; c.f = f;
  unsigned r = c.u + 0x7FFFu + ((c.u >> 16) & 1u);
  return (u16)(r >> 16);
}

__device__ __forceinline__ void gload16(const void* g, void* l) {
  __builtin_amdgcn_global_load_lds(
      (const __attribute__((address_space(1))) void*)(unsigned long long)g,
      (__attribute__((address_space(3))) void*)(unsigned)(unsigned long long)l,
      16, 0, 0);
}

// opaque ds_read_b128 (we do our own lgkmcnt/vmcnt accounting)
__device__ __forceinline__ bf16x8 dsr128(unsigned addr) {
  i32x4 r;
  asm volatile("ds_read_b128 %0, %1" : "=v"(r) : "v"(addr));
  return __builtin_bit_cast(bf16x8, r);
}

// ---------------------------------------------------------------------------
// 128x128 GEMM-BT, 4 waves (2x2), per-wave 64x64 (4x4 frags of 16x16x32).
// BK=32, 2-buffer LDS ring, 32KB total -> 3 blocks/CU co-resident (the m114
// inter-block overlap mechanism). Swizzled staging (conflict-free b128 reads)
// + LDS-staged epilogue (full-line stores, no write amplification).
// ---------------------------------------------------------------------------
template<int EBIAS, int EGELU, int ESCALE, int EROWSCALE, int OUTMODE, int ETRANS, int CSKIP, int CK>
__global__ __launch_bounds__(256, 3)
void gemm128(const u16* __restrict__ A, const u16* __restrict__ B,
             const float* __restrict__ bias, const float* __restrict__ rowscale,
             void* __restrict__ C,
             int K, int lda, int ldb, int ldc, float scale,
             long long sA, long long sB, long long sC, int sRS)
{
  __shared__ __align__(1024) u16 smem[16384];   // 32 KB (ring; epilogue reuse)

  // bijective XCD swizzle over x*y (z = batch)
  const int nwg = gridDim.x * gridDim.y;
  const int orig = blockIdx.y * gridDim.x + blockIdx.x;
  const int q = nwg >> 3, r = nwg & 7;
  const int xcd = orig & 7, pos0 = orig >> 3;
  const int wg = (xcd < r ? xcd * (q + 1) : r * (q + 1) + (xcd - r) * q) + pos0;
  const int bx = wg % gridDim.x, by = wg / gridDim.x;
  const int row0 = by * 128, col0 = bx * 128;
  if (CSKIP && col0 > row0 + 127) return;

  const int z = blockIdx.z;
  A += (size_t)z * sA;
  B += (size_t)z * sB;

  int nkt = K >> 5;
  if (CK) { int lim = (row0 + 128) >> 5; if (lim < nkt) nkt = lim; }

  const int tid  = threadIdx.x;
  const int wid  = tid >> 6;
  const int lane = tid & 63;
  const int wr = wid >> 1, wc = wid & 1;

  // staging (pre-swizzled source): lane l -> row +(l>>2), unit (l&3)^((l>>3)&3)
  const int srow = wid * 16 + (lane >> 2);
  const int sunit = (lane & 3) ^ ((lane >> 3) & 3);
  const char* gA = (const char*)A + ((size_t)(row0 + srow) * lda + sunit * 8) * 2;
  const char* gB = (const char*)B + ((size_t)(col0 + srow) * ldb + sunit * 8) * 2;
  char* lbase = (char*)smem;
  const size_t ldab = (size_t)64 * lda * 2;
  const size_t ldbb = (size_t)64 * ldb * 2;

  // per K-step: A tile 128x32 (8KB) + B tile (8KB); wave stages 4 x 1KB
  #define STG(t2) { char* lb = lbase + ((t2) & 1) * 16384; size_t kb = (size_t)(t2) * 64; \
      gload16(gA + kb,        lb + wid * 1024);                                           \
      gload16(gA + kb + ldab, lb + 4096 + wid * 1024);                                    \
      gload16(gB + kb,        lb + 8192 + wid * 1024);                                    \
      gload16(gB + kb + ldbb, lb + 8192 + 4096 + wid * 1024); }

  const int fr = lane & 15;
  const int ks16 = ((lane >> 4) & 3) * 16;
  const int xm = ((lane >> 1) & 3) << 4;      // == ((row>>1)&3)<<4 for our rows
  const unsigned sbase = (unsigned)(unsigned long long)(void*)smem;

  f32x4 acc[4][4] = {};

  STG(0);
  asm volatile("s_waitcnt vmcnt(0)");
  asm volatile("s_barrier" ::: "memory");

  for (int t = 0; t < nkt; ++t) {
    if (t + 1 < nkt) STG(t + 1);
    const unsigned cb = sbase + (t & 1) * 16384;
    bf16x8 af[4], bf[4];
#pragma unroll
    for (int m = 0; m < 4; ++m)
      af[m] = dsr128(cb + (((wr * 64 + m * 16 + fr) * 64 + ks16) ^ xm));
#pragma unroll
    for (int n = 0; n < 4; ++n)
      bf[n] = dsr128(cb + ((8192 + (wc * 64 + n * 16 + fr) * 64 + ks16) ^ xm));
    asm volatile("s_waitcnt lgkmcnt(0)");
    __builtin_amdgcn_sched_barrier(0);
    __builtin_amdgcn_s_setprio(1);
#pragma unroll
    for (int m = 0; m < 4; ++m)
#pragma unroll
      for (int n = 0; n < 4; ++n)
        acc[m][n] = __builtin_amdgcn_mfma_f32_16x16x32_bf16(af[m], bf[n], acc[m][n], 0, 0, 0);
    __builtin_amdgcn_s_setprio(0);
    asm volatile("s_waitcnt vmcnt(0)");   // next buffer fully landed
    asm volatile("s_barrier" ::: "memory");
  }
  #undef STG

  // ---- epilogue via LDS (loop's final barrier makes smem reusable) ----
  char* sm = (char*)smem;
  const int r4 = (lane >> 4) * 4;

  if (OUTMODE == 1) {
    // f32 out: 2 passes, each 128 lines x 256 B (half the cols)
#pragma unroll
    for (int p = 0; p < 2; ++p) {
      if (wc == p) {
#pragma unroll
        for (int n = 0; n < 4; ++n) {
          const int col = col0 + wc * 64 + n * 16 + fr;
          const int pb = (n * 16 + fr) * 4;
          float bia = EBIAS ? bias[col] : 0.0f;
#pragma unroll
          for (int m = 0; m < 4; ++m) {
#pragma unroll
            for (int j = 0; j < 4; ++j) {
              const int line = wr * 64 + m * 16 + r4 + j;
              float xv = acc[m][n][j];
              if (EBIAS)     xv += bia;
              if (ESCALE)    xv *= scale;
              if (EROWSCALE) xv *= rowscale[z * sRS + row0 + line];
              if (EGELU)     xv = 0.5f * xv * (1.0f + erff(xv * 0.70710678118f));
              *(float*)(sm + ((line * 256 + pb) ^ ((line & 7) << 4))) = xv;
            }
          }
        }
      }
      __syncthreads();
      float* Cb = (float*)C + (size_t)z * sC;
#pragma unroll
      for (int i = 0; i < 8; ++i) {
        const int o = i * 4096 + tid * 16;
        const int line = o >> 8, ps = o & 255;
        f32x4 v = *(const f32x4*)(sm + ((line * 256 + ps) ^ ((line & 7) << 4)));
        *(f32x4*)((char*)(Cb + (size_t)(row0 + line) * ldc + col0 + p * 64) + ps) = v;
      }
      __syncthreads();
    }
  } else if (ETRANS) {
    // transposed bf16 out: line = local col (128), pos = local row * 2
#pragma unroll
    for (int n = 0; n < 4; ++n) {
      const int col = col0 + wc * 64 + n * 16 + fr;
      const int line = wc * 64 + n * 16 + fr;
      float bia = EBIAS ? bias[col] : 0.0f;
#pragma unroll
      for (int m = 0; m < 4; ++m) {
        const int rb = wr * 64 + m * 16 + r4;
        u16x4 pk;
#pragma unroll
        for (int j = 0; j < 4; ++j) {
          float xv = acc[m][n][j];
          if (EBIAS) xv += bia;
          pk[j] = f2bf(xv);
        }
        *(u16x4*)(sm + ((line * 256 + rb * 2) ^ ((line & 7) << 4))) = pk;
      }
    }
    __syncthreads();
    u16* Cb = (u16*)C + (size_t)(row0 >> 11) * (DD * SS) + (row0 & (SS - 1));
#pragma unroll
    for (int i = 0; i < 8; ++i) {
      const int o = i * 4096 + tid * 16;
      const int line = o >> 8, ps = o & 255;
      f32x4 v = *(const f32x4*)(sm + ((line * 256 + ps) ^ ((line & 7) << 4)));
      *(f32x4*)((char*)(Cb + (size_t)(col0 + line) * SS) + ps) = v;
    }
  } else {
    // 2-byte out (bf16 OUTMODE=0, f16 OUTMODE=2): line = row, 256B/line
#pragma unroll
    for (int n = 0; n < 4; ++n) {
      const int col = col0 + wc * 64 + n * 16 + fr;
      const int pc = (wc * 64 + n * 16 + fr) * 2;
      float bia = EBIAS ? bias[col] : 0.0f;
#pragma unroll
      for (int m = 0; m < 4; ++m) {
#pragma unroll
        for (int j = 0; j < 4; ++j) {
          const int line = wr * 64 + m * 16 + r4 + j;
          float xv = acc[m][n][j];
          if (EBIAS)     xv += bia;
          if (ESCALE)    xv *= scale;
          if (EROWSCALE) xv *= rowscale[z * sRS + row0 + line];
          if (EGELU)     xv = 0.5f * xv * (1.0f + erff(xv * 0.70710678118f));
          u16 u;
          if (OUTMODE == 2) { union { u16 s; _Float16 h; } cu; cu.h = (_Float16)xv; u = cu.s; }
          else u = f2bf(xv);
          *(u16*)(sm + ((line * 256 + pc) ^ ((line & 7) << 4))) = u;
        }
      }
    }
    __syncthreads();
    u16* Cb = (u16*)C + (size_t)z * sC + col0;
#pragma unroll
    for (int i = 0; i < 8; ++i) {
      const int o = i * 4096 + tid * 16;
      const int line = o >> 8, ps = o & 255;
      f32x4 v = *(const f32x4*)(sm + ((line * 256 + ps) ^ ((line & 7) << 4)));
      *(f32x4*)((char*)(Cb + (size_t)(row0 + line) * ldc) + ps) = v;
    }
  }
}

// f32 -> bf16 convert, 4 elems/thread
__global__ __launch_bounds__(256) void cvt_bf16_k(const float* __restrict__ in, u16* __restrict__ out, int n4) {
  int i = blockIdx.x * blockDim.x + threadIdx.x;
  if (i < n4) {
    float4 v = ((const float4*)in)[i];
    u16x4 o;
    o.x = f2bf(v.x); o.y = f2bf(v.y); o.z = f2bf(v.z); o.w = f2bf(v.w);
    ((u16x4*)out)[i] = o;
  }
}

// batched row softmax over f16 scores, in-place rewrite as unnormalized bf16 P
__global__ __launch_bounds__(256) void softmax_k(u16* __restrict__ sc, float* __restrict__ rinv, int rows0) {
  const int widx = blockIdx.x * 4 + (threadIdx.x >> 6);
  const int lane = threadIdx.x & 63;
  u16* row = sc + (size_t)widx * SS;
  const int L = (widx & (SS - 1)) + 1;
  float mx = -1e30f;
  for (int k = 0; k < 4; ++k) {
    const int j0 = k * 512 + lane * 8;
    if (j0 < L) {
      u16x8 v = *(const u16x8*)(row + j0);
      int lim = L - j0; if (lim > 8) lim = 8;
#pragma unroll
      for (int e = 0; e < 8; ++e) {
        if (e < lim) { union { u16 u; _Float16 h; } c; c.u = v[e]; mx = fmaxf(mx, (float)c.h); }
      }
    }
  }
#pragma unroll
  for (int o = 32; o >= 1; o >>= 1) mx = fmaxf(mx, __shfl_xor(mx, o));
  float s = 0.0f;
  for (int k = 0; k < 4; ++k) {
    const int j0 = k * 512 + lane * 8;
    u16x8 v = *(const u16x8*)(row + j0);
    u16x8 w;
#pragma unroll
    for (int e = 0; e < 8; ++e) {
      const int j = j0 + e;
      float ev = 0.0f;
      if (j < L) { union { u16 u; _Float16 h; } c; c.u = v[e]; ev = __expf((float)c.h - mx); s += ev; }
      w[e] = f2bf(ev);
    }
    *(u16x8*)(row + j0) = w;
  }
#pragma unroll
  for (int o = 32; o >= 1; o >>= 1) s += __shfl_xor(s, o);
  if (lane == 0) rinv[rows0 + widx] = 1.0f / s;
}

extern "C" void kernel_launch(void* const* d_in, const int* in_sizes, int n_in,
                              void* d_out, int out_size, void* d_ws, size_t ws_size,
                              hipStream_t stream) {
  const float* x  = (const float*)d_in[0];
  const float* Wq = (const float*)d_in[1];
  const float* bq = (const float*)d_in[2];
  const float* Wk = (const float*)d_in[3];
  const float* bk = (const float*)d_in[4];
  const float* Wv = (const float*)d_in[5];
  const float* bv = (const float*)d_in[6];
  const float* W1 = (const float*)d_in[7];
  const float* b1 = (const float*)d_in[8];
  const float* W2 = (const float*)d_in[9];
  const float* b2 = (const float*)d_in[10];

  char* ws = (char*)d_ws;
  u16*  xb   = (u16*)(ws);                       // 32 MB (later: att)
  u16*  Wqb  = (u16*)(ws + 33554432);
  u16*  Wkb  = (u16*)(ws + 35651584);
  u16*  Wvb  = (u16*)(ws + 37748736);
  u16*  W1b  = (u16*)(ws + 39845888);
  u16*  W2b  = (u16*)(ws + 48234496);
  u16*  Qb   = (u16*)(ws + 56623104);            // 32 MB
  u16*  Kb   = (u16*)(ws + 90177536);            // 32 MB
  u16*  Vtb  = (u16*)(ws + 123731968);           // 32 MB
  float* rinv = (float*)(ws + 157286400);        // 64 KB
  u16*  big  = (u16*)(ws + 157351936);           // scores/P region; later h
  u16*  att  = xb;

  const size_t base = 157351936ull;
  const size_t avail = ws_size > base ? ws_size - base : 0;
  int GB = 8; while (GB > 1 && (size_t)GB * 8388608ull > avail) GB >>= 1;
  int MC = 8192; while (MC > 2048 && (size_t)MC * 8192ull > avail) MC >>= 1;

  // --- converts ---
  cvt_bf16_k<<<MTOT * DD / 4 / 256, 256, 0, stream>>>(x, xb, MTOT * DD / 4);
  cvt_bf16_k<<<DD * DD / 4 / 256, 256, 0, stream>>>(Wq, Wqb, DD * DD / 4);
  cvt_bf16_k<<<DD * DD / 4 / 256, 256, 0, stream>>>(Wk, Wkb, DD * DD / 4);
  cvt_bf16_k<<<DD * DD / 4 / 256, 256, 0, stream>>>(Wv, Wvb, DD * DD / 4);
  cvt_bf16_k<<<DFFN * DD / 4 / 256, 256, 0, stream>>>(W1, W1b, DFFN * DD / 4);
  cvt_bf16_k<<<DFFN * DD / 4 / 256, 256, 0, stream>>>(W2, W2b, DFFN * DD / 4);

  // --- QKV projections (grid 8x128 = 1024 blocks each) ---
  gemm128<1,0,0,0,0,0,0,0><<<dim3(DD/128, MTOT/128), 256, 0, stream>>>(
      xb, Wqb, bq, nullptr, (void*)Qb, DD, DD, DD, DD, 0.f, 0, 0, 0, 0);
  gemm128<1,0,0,0,0,0,0,0><<<dim3(DD/128, MTOT/128), 256, 0, stream>>>(
      xb, Wkb, bk, nullptr, (void*)Kb, DD, DD, DD, DD, 0.f, 0, 0, 0, 0);
  gemm128<1,0,0,0,0,1,0,0><<<dim3(DD/128, MTOT/128), 256, 0, stream>>>(
      xb, Wvb, bv, nullptr, (void*)Vtb, DD, DD, DD, DD, 0.f, 0, 0, 0, 0);

  // --- attention, batched over z in groups of GB ---
  for (int b0 = 0; b0 < NB; b0 += GB) {
    gemm128<0,0,1,0,2,0,1,0><<<dim3(SS/128, SS/128, GB), 256, 0, stream>>>(
        Qb + (size_t)b0 * SS * DD, Kb + (size_t)b0 * SS * DD, nullptr, nullptr,
        (void*)big, DD, DD, DD, SS, 0.03125f,
        (long long)SS * DD, (long long)SS * DD, (long long)SS * SS, 0);
    softmax_k<<<GB * SS / 4, 256, 0, stream>>>(big, rinv, b0 * SS);
    gemm128<0,0,0,1,0,0,0,1><<<dim3(DD/128, SS/128, GB), 256, 0, stream>>>(
        big, Vtb + (size_t)b0 * DD * SS, nullptr, rinv + (size_t)b0 * SS,
        (void*)(att + (size_t)b0 * SS * DD), SS, SS, SS, DD, 0.f,
        (long long)SS * SS, (long long)DD * SS, (long long)SS * DD, SS);
  }

  // --- MLP in chunks of MC rows ---
  for (int c = 0; c < MTOT / MC; ++c) {
    u16* h = big;
    gemm128<1,1,0,0,0,0,0,0><<<dim3(DFFN/128, MC/128), 256, 0, stream>>>(
        att + (size_t)c * MC * DD, W1b, b1, nullptr, (void*)h,
        DD, DD, DD, DFFN, 0.f, 0, 0, 0, 0);
    gemm128<1,0,0,0,1,0,0,0><<<dim3(DD/128, MC/128), 256, 0, stream>>>(
        h, W2b, b2, nullptr, (void*)((float*)d_out + (size_t)c * MC * DD),
        DFFN, DFFN, DFFN, DD, 0.f, 0, 0, 0, 0);
  }
}